// Round 1
// baseline (506.792 us; speedup 1.0000x reference)
//
#include <hip/hip_runtime.h>

// Butterfly (untied, increasing stride), batch=32768, n=1024, m=10 stages, nstack=1.
// One wave owns B_ROWS=8 full rows entirely in registers (as 4 float2 row-pairs).
// Element->lane layout: e = r*256 + lane*4 + j  (r=0..3, j=0..3; 16 floats/lane/row).
//   strides 1,2    : intra-lane, position xor 1,2 (j bits)
//   strides 4..128 : cross-lane, __shfl_xor masks 1,2,4,8,16,32
//   strides 256,512: intra-lane, position xor 4,8 (r bits)
// Twiddle loads amortized over 8 rows; twiddle is 80KB -> L2 resident.

constexpr int N = 1024;
constexpr int B_ROWS = 8;   // rows per wave
constexpr int WAVES = 4;    // waves per block (block = 256 threads)

__global__ __launch_bounds__(256, 2)
void butterfly_kernel(const float* __restrict__ x,
                      const float* __restrict__ tw,    // [10][512][2][2]
                      const float* __restrict__ bias,  // [1024]
                      float* __restrict__ out)
{
    const int lane  = threadIdx.x & 63;
    const int waveg = blockIdx.x * WAVES + (threadIdx.x >> 6);
    const size_t row0 = (size_t)waveg * B_ROWS;

    float2 v[4][16];   // [row-pair q][position p], .x = row 2q, .y = row 2q+1

    // ---- load: coalesced float4 per row (lane*16B stride) ----
    #pragma unroll
    for (int q = 0; q < 4; ++q) {
        const float* p0 = x + (row0 + 2 * q) * N + lane * 4;
        const float* p1 = p0 + N;
        #pragma unroll
        for (int r = 0; r < 4; ++r) {
            const float4 a = *(const float4*)(p0 + r * 256);
            const float4 b = *(const float4*)(p1 + r * 256);
            v[q][r * 4 + 0] = make_float2(a.x, b.x);
            v[q][r * 4 + 1] = make_float2(a.y, b.y);
            v[q][r * 4 + 2] = make_float2(a.z, b.z);
            v[q][r * 4 + 3] = make_float2(a.w, b.w);
        }
    }

    // ---- 10 butterfly stages ----
    #pragma unroll
    for (int stage = 0; stage < 10; ++stage) {
        const int s = 1 << stage;
        const float* tws = tw + (stage << 11);   // 512*4 floats per stage
        float tA[16], tB[16];
        #pragma unroll
        for (int p = 0; p < 16; ++p) {
            const int e  = ((p >> 2) << 8) | (lane << 2) | (p & 3);
            const int i  = (e >> stage) & 1;
            const int pr = ((e >> (stage + 1)) << stage) | (e & (s - 1));
            const float2 tt = *(const float2*)(tws + pr * 4 + i * 2);
            // out(e) = tA*in(e) + tB*in(e^s); tA = t[p][i][i], tB = t[p][i][1-i]
            tA[p] = i ? tt.y : tt.x;
            tB[p] = i ? tt.x : tt.y;
        }
        if (s >= 4 && s <= 128) {
            const int m = s >> 2;   // lane xor mask
            #pragma unroll
            for (int q = 0; q < 4; ++q) {
                #pragma unroll
                for (int p = 0; p < 16; ++p) {
                    const float px = __shfl_xor(v[q][p].x, m, 64);
                    const float py = __shfl_xor(v[q][p].y, m, 64);
                    v[q][p].x = tA[p] * v[q][p].x + tB[p] * px;
                    v[q][p].y = tA[p] * v[q][p].y + tB[p] * py;
                }
            }
        } else {
            const int pm = (s == 1) ? 1 : (s == 2) ? 2 : (s == 256) ? 4 : 8;
            #pragma unroll
            for (int q = 0; q < 4; ++q) {
                #pragma unroll
                for (int p = 0; p < 16; ++p) {
                    if (p & pm) continue;          // handle pair (p, p|pm) together
                    const int p2 = p | pm;
                    const float2 a = v[q][p];
                    const float2 b = v[q][p2];
                    v[q][p].x  = tA[p]  * a.x + tB[p]  * b.x;
                    v[q][p].y  = tA[p]  * a.y + tB[p]  * b.y;
                    v[q][p2].x = tA[p2] * b.x + tB[p2] * a.x;
                    v[q][p2].y = tA[p2] * b.y + tB[p2] * a.y;
                }
            }
        }
    }

    // ---- store with bias ----
    float4 bb[4];
    #pragma unroll
    for (int r = 0; r < 4; ++r)
        bb[r] = *(const float4*)(bias + r * 256 + lane * 4);

    #pragma unroll
    for (int q = 0; q < 4; ++q) {
        float* o0 = out + (row0 + 2 * q) * N + lane * 4;
        float* o1 = o0 + N;
        #pragma unroll
        for (int r = 0; r < 4; ++r) {
            float4 a, b;
            a.x = v[q][r * 4 + 0].x + bb[r].x;  b.x = v[q][r * 4 + 0].y + bb[r].x;
            a.y = v[q][r * 4 + 1].x + bb[r].y;  b.y = v[q][r * 4 + 1].y + bb[r].y;
            a.z = v[q][r * 4 + 2].x + bb[r].z;  b.z = v[q][r * 4 + 2].y + bb[r].z;
            a.w = v[q][r * 4 + 3].x + bb[r].w;  b.w = v[q][r * 4 + 3].y + bb[r].w;
            *(float4*)(o0 + r * 256) = a;
            *(float4*)(o1 + r * 256) = b;
        }
    }
}

extern "C" void kernel_launch(void* const* d_in, const int* in_sizes, int n_in,
                              void* d_out, int out_size, void* d_ws, size_t ws_size,
                              hipStream_t stream) {
    const float* x    = (const float*)d_in[0];   // [batch][1024]
    const float* tw   = (const float*)d_in[1];   // [1][10][512][2][2]
    const float* bias = (const float*)d_in[2];   // [1024]
    float* out        = (float*)d_out;

    const int batch = in_sizes[0] / N;           // 32768
    const int blocks = batch / (B_ROWS * WAVES); // 1024
    hipLaunchKernelGGL(butterfly_kernel, dim3(blocks), dim3(256), 0, stream,
                       x, tw, bias, out);
}